// Round 2
// baseline (1208.506 us; speedup 1.0000x reference)
//
#include <hip/hip_runtime.h>
#include <math.h>

#define NTOK 65536   // B*T = 8*8192
#define T_   8192
#define C_   512

typedef short short8 __attribute__((ext_vector_type(8)));
typedef float f32x4  __attribute__((ext_vector_type(4)));

#define GLDS(gp, lp) __builtin_amdgcn_global_load_lds( \
    (__attribute__((address_space(1))) void*)(void*)(gp), \
    (__attribute__((address_space(3))) void*)(lp), 16, 0, 0)

__device__ __forceinline__ unsigned short f2bf(float f){
  unsigned x = __float_as_uint(f);
  x += 0x7fffu + ((x >> 16) & 1u);
  return (unsigned short)(x >> 16);
}
__device__ __forceinline__ float bflo(unsigned p){ return __uint_as_float(p << 16); }
__device__ __forceinline__ float bfhi(unsigned p){ return __uint_as_float(p & 0xffff0000u); }
__device__ __forceinline__ float bfs(unsigned short u){ return __uint_as_float(((unsigned)u) << 16); }
__device__ __forceinline__ unsigned pack2(float a, float b){
  return (unsigned)f2bf(a) | ((unsigned)f2bf(b) << 16);
}

// ---------------- weight prep ----------------
__global__ __launch_bounds__(256) void k_convert(const float* __restrict__ src,
                                                 unsigned short* __restrict__ dst, int n){
  int i = blockIdx.x * 256 + threadIdx.x;
  if (i < n) dst[i] = f2bf(src[i]);
}
// dst[s*R + r] = src[r*S + s]   (src is R x S row-major f32, dst is S x R bf16)
__global__ __launch_bounds__(256) void k_transpose(const float* __restrict__ src,
                                                   unsigned short* __restrict__ dst, int R, int S){
  int i = blockIdx.x * 256 + threadIdx.x;
  if (i < R * S){
    int s = i / R;
    int r = i - s * R;
    dst[i] = f2bf(src[(size_t)r * S + s]);
  }
}

// ---------------- layernorm: one block per row (C=512) ----------------
__global__ __launch_bounds__(256) void k_ln(const float* __restrict__ x,
                                            const float* __restrict__ g,
                                            const float* __restrict__ b,
                                            unsigned* __restrict__ outbf){
  int row = blockIdx.x;
  int t = threadIdx.x;
  float2 v = ((const float2*)(x + (size_t)row * C_))[t];
  float s = v.x + v.y, ss = v.x * v.x + v.y * v.y;
  #pragma unroll
  for (int o = 32; o; o >>= 1){ s += __shfl_down(s, o); ss += __shfl_down(ss, o); }
  __shared__ float red[8];
  if ((t & 63) == 0){ red[t >> 6] = s; red[4 + (t >> 6)] = ss; }
  __syncthreads();
  float S = red[0] + red[1] + red[2] + red[3];
  float Q = red[4] + red[5] + red[6] + red[7];
  float mu  = S * (1.0f / C_);
  float var = Q * (1.0f / C_) - mu * mu;
  float rs = rsqrtf(var + 1e-5f);
  float y0 = (v.x - mu) * rs * g[2*t]   + b[2*t];
  float y1 = (v.y - mu) * rs * g[2*t+1] + b[2*t+1];
  outbf[(size_t)row * 256 + t] = pack2(y0, y1);
}

// ---------------- depthwise causal conv K=3 over T, chunk-local output ----------------
__global__ __launch_bounds__(256) void k_conv(const unsigned* __restrict__ xn,
                                              const float* __restrict__ w,     // C*3
                                              const float* __restrict__ bias,  // C
                                              unsigned* __restrict__ loc,      // chunk-local
                                              int base){
  size_t idx = (size_t)blockIdx.x * 256 + threadIdx.x;
  size_t n = (idx >> 8) + (size_t)base;   // global token index
  int cp = (int)(idx & 255);              // channel pair
  int t = (int)(n & (T_ - 1));
  unsigned v0 = xn[n * 256 + cp];
  unsigned v1 = (t >= 1) ? xn[(n - 1) * 256 + cp] : 0u;
  unsigned v2 = (t >= 2) ? xn[(n - 2) * 256 + cp] : 0u;
  int c = cp * 2;
  // out[t] = x[t]*w[2] + x[t-1]*w[1] + x[t-2]*w[0]  (cross-correlation, pad (2,0))
  float r0 = bias[c]     + bflo(v0)*w[c*3+2] + bflo(v1)*w[c*3+1] + bflo(v2)*w[c*3+0];
  float r1 = bias[c + 1] + bfhi(v0)*w[c*3+5] + bfhi(v1)*w[c*3+4] + bfhi(v2)*w[c*3+3];
  loc[idx] = pack2(r0, r1);
}

// ---------------- in-place row softmax over M=512, bf16 ----------------
__global__ __launch_bounds__(256) void k_softmax_ip(unsigned* __restrict__ sw){
  int row = blockIdx.x;
  int t = threadIdx.x;
  unsigned p = sw[(size_t)row * 256 + t];
  float vx = bflo(p), vy = bfhi(p);
  float mx = fmaxf(vx, vy);
  #pragma unroll
  for (int o = 32; o; o >>= 1) mx = fmaxf(mx, __shfl_xor(mx, o));
  __shared__ float red[8];
  int w = t >> 6;
  if ((t & 63) == 0) red[w] = mx;
  __syncthreads();
  mx = fmaxf(fmaxf(red[0], red[1]), fmaxf(red[2], red[3]));
  float e0 = expf(vx - mx), e1 = expf(vy - mx);
  float s = e0 + e1;
  #pragma unroll
  for (int o = 32; o; o >>= 1) s += __shfl_xor(s, o);
  if ((t & 63) == 0) red[4 + w] = s;
  __syncthreads();
  float inv = 1.0f / (red[4] + red[5] + red[6] + red[7]);
  sw[(size_t)row * 256 + t] = pack2(e0 * inv, e1 * inv);
}

// ---------------- bf16 MFMA GEMM, 128x128 tile, BK=32, 4 waves ----------------
// A: M x K bf16 row-major. Bt: N x K bf16 row-major (B^T layout).
// EPI: 1=bf16, 3=gelu(acc+bias)->bf16, 4=acc+bias+add->f32
template<int EPI>
__global__ __launch_bounds__(256) void k_gemm(const unsigned short* __restrict__ A,
                                              const unsigned short* __restrict__ Bt,
                                              void* __restrict__ out,
                                              const float* __restrict__ bias,
                                              const float* __restrict__ add,
                                              int K, int N){
  __shared__ char smem[16384];   // A tile 8KB | B tile 8KB, each [128][32] bf16
  const int tid  = threadIdx.x;
  const int lane = tid & 63;
  const int w    = tid >> 6;
  const int wr   = w >> 1, wc = w & 1;
  const long brow = (long)blockIdx.x * 128;
  const long bcol = (long)blockIdx.y * 128;

  f32x4 acc[4][4];
  #pragma unroll
  for (int i = 0; i < 4; i++)
    #pragma unroll
    for (int j = 0; j < 4; j++){ f32x4 z = {0.f,0.f,0.f,0.f}; acc[i][j] = z; }

  const char* Abase = (const char*)(A + brow * K);
  const char* Bbase = (const char*)(Bt + bcol * K);
  const int r0 = tid >> 2;            // row within tile for staging
  const int c0 = (tid & 3) * 16;      // byte offset within 64B row
  char* sA = smem;
  char* sB = smem + 8192;
  const unsigned wbase = (unsigned)(w * 1024);   // wave-uniform LDS base

  for (int k0 = 0; k0 < K; k0 += 32){
    __syncthreads();
    {
      const char* g0 = Abase + ((long)r0 * K + k0) * 2 + c0;
      const char* g1 = Abase + ((long)(64 + r0) * K + k0) * 2 + c0;
      GLDS(g0, sA + wbase);
      GLDS(g1, sA + 4096 + wbase);
      const char* h0 = Bbase + ((long)r0 * K + k0) * 2 + c0;
      const char* h1 = Bbase + ((long)(64 + r0) * K + k0) * 2 + c0;
      GLDS(h0, sB + wbase);
      GLDS(h1, sB + 4096 + wbase);
    }
    __syncthreads();
    short8 af[4], bfr[4];
    const int lr = lane & 15;
    const int lk = (lane >> 4) * 16;
    #pragma unroll
    for (int mi = 0; mi < 4; mi++)
      af[mi] = *(const short8*)(sA + (wr * 64 + mi * 16 + lr) * 64 + lk);
    #pragma unroll
    for (int ni = 0; ni < 4; ni++)
      bfr[ni] = *(const short8*)(sB + (wc * 64 + ni * 16 + lr) * 64 + lk);
    #pragma unroll
    for (int mi = 0; mi < 4; mi++)
      #pragma unroll
      for (int ni = 0; ni < 4; ni++)
        acc[mi][ni] = __builtin_amdgcn_mfma_f32_16x16x32_bf16(af[mi], bfr[ni], acc[mi][ni], 0, 0, 0);
  }

  // epilogue: C/D layout col=lane&15, row=(lane>>4)*4+j
  const long rbase = brow + wr * 64;
  const int  cbase = (int)bcol + wc * 64;
  #pragma unroll
  for (int mi = 0; mi < 4; mi++){
    #pragma unroll
    for (int ni = 0; ni < 4; ni++){
      long rg0 = rbase + mi * 16 + (lane >> 4) * 4;
      int  cg  = cbase + ni * 16 + (lane & 15);
      #pragma unroll
      for (int j = 0; j < 4; j++){
        long rg = rg0 + j;
        long oi = rg * (long)N + cg;
        float v = acc[mi][ni][j];
        if (EPI == 1){
          ((unsigned short*)out)[oi] = f2bf(v);
        } else if (EPI == 3){
          v += bias[cg];
          v = 0.5f * v * (1.0f + erff(v * 0.70710678118654752f));
          ((unsigned short*)out)[oi] = f2bf(v);
        } else {
          v += bias[cg] + add[oi];
          ((float*)out)[oi] = v;
        }
      }
    }
  }
}

// ------- fused gates GEMM + sigmoid + gated combine + residual -> x2 (f32) -------
// A: xn chunk [S x 512]. Bt = gwT [1024 x 512]. Block covers cols [bcol,bcol+128)
// of BOTH halves (lg at bcol, gg at 512+bcol). Epilogue reads local/ctx (bf16,
// chunk-local) and x (f32, chunk-offset), writes x2 to d_out (chunk-offset).
__global__ __launch_bounds__(256) void k_gatecomb(const unsigned short* __restrict__ A,
                                                  const unsigned short* __restrict__ Bt,
                                                  const float* __restrict__ gb,      // 1024
                                                  const unsigned short* __restrict__ loc,
                                                  const unsigned short* __restrict__ ctx,
                                                  const float* __restrict__ x,
                                                  float* __restrict__ x2){
  __shared__ char smem[24576];   // A 8KB | Bl 8KB | Bg 8KB
  const int tid  = threadIdx.x;
  const int lane = tid & 63;
  const int w    = tid >> 6;
  const int wr   = w >> 1, wc = w & 1;
  const long brow = (long)blockIdx.x * 128;
  const int  bcol = blockIdx.y * 128;
  const int K = 512;

  f32x4 accL[4][4], accG[4][4];
  #pragma unroll
  for (int i = 0; i < 4; i++)
    #pragma unroll
    for (int j = 0; j < 4; j++){
      f32x4 z = {0.f,0.f,0.f,0.f}; accL[i][j] = z; accG[i][j] = z;
    }

  const char* Abase  = (const char*)(A + brow * (long)K);
  const char* Blbase = (const char*)(Bt + (long)bcol * K);
  const char* Bgbase = (const char*)(Bt + (long)(512 + bcol) * K);
  const int r0 = tid >> 2;
  const int c0 = (tid & 3) * 16;
  char* sA = smem;
  char* sBl = smem + 8192;
  char* sBg = smem + 16384;
  const unsigned wbase = (unsigned)(w * 1024);

  for (int k0 = 0; k0 < K; k0 += 32){
    __syncthreads();
    GLDS(Abase  + ((long)r0 * K + k0) * 2 + c0,        sA  + wbase);
    GLDS(Abase  + ((long)(64 + r0) * K + k0) * 2 + c0, sA  + 4096 + wbase);
    GLDS(Blbase + ((long)r0 * K + k0) * 2 + c0,        sBl + wbase);
    GLDS(Blbase + ((long)(64 + r0) * K + k0) * 2 + c0, sBl + 4096 + wbase);
    GLDS(Bgbase + ((long)r0 * K + k0) * 2 + c0,        sBg + wbase);
    GLDS(Bgbase + ((long)(64 + r0) * K + k0) * 2 + c0, sBg + 4096 + wbase);
    __syncthreads();
    short8 af[4], bl[4], bg[4];
    const int lr = lane & 15;
    const int lk = (lane >> 4) * 16;
    #pragma unroll
    for (int mi = 0; mi < 4; mi++)
      af[mi] = *(const short8*)(sA + (wr * 64 + mi * 16 + lr) * 64 + lk);
    #pragma unroll
    for (int ni = 0; ni < 4; ni++){
      bl[ni] = *(const short8*)(sBl + (wc * 64 + ni * 16 + lr) * 64 + lk);
      bg[ni] = *(const short8*)(sBg + (wc * 64 + ni * 16 + lr) * 64 + lk);
    }
    #pragma unroll
    for (int mi = 0; mi < 4; mi++)
      #pragma unroll
      for (int ni = 0; ni < 4; ni++){
        accL[mi][ni] = __builtin_amdgcn_mfma_f32_16x16x32_bf16(af[mi], bl[ni], accL[mi][ni], 0, 0, 0);
        accG[mi][ni] = __builtin_amdgcn_mfma_f32_16x16x32_bf16(af[mi], bg[ni], accG[mi][ni], 0, 0, 0);
      }
  }

  const long rbase = brow + wr * 64;
  const int  cb    = bcol + wc * 64;
  #pragma unroll
  for (int mi = 0; mi < 4; mi++){
    #pragma unroll
    for (int ni = 0; ni < 4; ni++){
      long rg0 = rbase + mi * 16 + (lane >> 4) * 4;
      int  cg  = cb + ni * 16 + (lane & 15);
      float bL = gb[cg], bG = gb[512 + cg];
      #pragma unroll
      for (int j = 0; j < 4; j++){
        long rg = rg0 + j;
        long oi = rg * 512 + cg;
        float vL = 1.0f / (1.0f + expf(-(accL[mi][ni][j] + bL)));
        float vG = 1.0f / (1.0f + expf(-(accG[mi][ni][j] + bG)));
        float lv = bfs(loc[oi]);
        float cv = bfs(ctx[oi]);
        x2[oi] = x[oi] + vL * lv + vG * cv;
      }
    }
  }
}

// ---------------- launch ----------------
extern "C" void kernel_launch(void* const* d_in, const int* in_sizes, int n_in,
                              void* d_out, int out_size, void* d_ws, size_t ws_size,
                              hipStream_t stream){
  const float* x      = (const float*)d_in[0];
  const float* conv_w = (const float*)d_in[1];
  const float* conv_b = (const float*)d_in[2];
  const float* mb     = (const float*)d_in[3];
  const float* gate_w = (const float*)d_in[4];
  const float* gate_b = (const float*)d_in[5];
  const float* w1     = (const float*)d_in[6];
  const float* b1     = (const float*)d_in[7];
  const float* w2     = (const float*)d_in[8];
  const float* b2     = (const float*)d_in[9];
  const float* ln1g   = (const float*)d_in[10];
  const float* ln1b   = (const float*)d_in[11];
  const float* ln2g   = (const float*)d_in[12];
  const float* ln2b   = (const float*)d_in[13];

  char* ws = (char*)d_ws;
  const size_t MB = 1024ull * 1024ull;
  // weight prep region: 0..8MB
  unsigned short* mb_bf = (unsigned short*)(ws + 0);
  unsigned short* mbT   = (unsigned short*)(ws + 512 * 1024);
  unsigned short* gwT   = (unsigned short*)(ws + 1 * MB);
  unsigned short* w1T   = (unsigned short*)(ws + 2 * MB);
  unsigned short* w2T   = (unsigned short*)(ws + 4 * MB);
  unsigned short* xn    = (unsigned short*)(ws + 8 * MB);   // 64MB; reused as h
  char* region = ws + 72 * MB;

  // chunk size tier from ws_size (deterministic):
  // peak = 72MB + 3*S KB (middle) ; f1 = 4*(S/2) KB <= 3*S KB
  int S;
  if      (ws_size >= 264 * MB) S = 65536;
  else if (ws_size >= 120 * MB) S = 16384;
  else                          S = 4096;
  const int S2 = S / 2;
  const int NC  = NTOK / S;
  const int NC2 = NTOK / S2;

  unsigned short* loc_c = (unsigned short*)(region);
  unsigned short* ctx_c = (unsigned short*)(region + (size_t)S * 1024);
  unsigned short* sco_c = (unsigned short*)(region + (size_t)S * 2048);
  unsigned short* f1    = (unsigned short*)(region);   // reuses loc/ctx after middle phase

  // weight prep (bf16 + transposes to N x K layout)
  k_convert  <<<1024, 256, 0, stream>>>(mb, mb_bf, 512 * 512);
  k_transpose<<<1024, 256, 0, stream>>>(mb, mbT, 512, 512);
  k_transpose<<<2048, 256, 0, stream>>>(gate_w, gwT, 512, 1024);
  k_transpose<<<4096, 256, 0, stream>>>(w1, w1T, 512, 2048);
  k_transpose<<<4096, 256, 0, stream>>>(w2, w2T, 2048, 512);

  // LN1 -> xn (bf16, full)
  k_ln<<<NTOK, 256, 0, stream>>>(x, ln1g, ln1b, (unsigned*)xn);

  // middle phase, chunked over tokens
  for (int c = 0; c < NC; c++){
    const int base = c * S;
    const unsigned short* xnc = xn + (size_t)base * 512;
    // depthwise causal conv -> local (bf16, chunk-local)
    k_conv<<<S, 256, 0, stream>>>((const unsigned*)xn, conv_w, conv_b,
                                  (unsigned*)loc_c, base);
    // scores = xn @ mb^T (bf16)
    k_gemm<1><<<dim3(S / 128, 4), 256, 0, stream>>>(xnc, mb_bf, sco_c,
                                                    nullptr, nullptr, 512, 512);
    // softmax rows in-place
    k_softmax_ip<<<S, 256, 0, stream>>>((unsigned*)sco_c);
    // ctx = weights @ mb (bf16)
    k_gemm<1><<<dim3(S / 128, 4), 256, 0, stream>>>(sco_c, mbT, ctx_c,
                                                    nullptr, nullptr, 512, 512);
    // gates + sigmoid + combine + residual -> x2 (f32, into d_out)
    k_gatecomb<<<dim3(S / 128, 4), 256, 0, stream>>>(xnc, gwT, gate_b,
                                                     loc_c, ctx_c,
                                                     x + (size_t)base * 512,
                                                     (float*)d_out + (size_t)base * 512);
  }

  // LN2: h = LN(x2) (bf16, reuse xn buffer)
  k_ln<<<NTOK, 256, 0, stream>>>((const float*)d_out, ln2g, ln2b, (unsigned*)xn);

  // FFN, chunked
  for (int c = 0; c < NC2; c++){
    const int base = c * S2;
    // f1 = gelu(h @ w1 + b1) (bf16)
    k_gemm<3><<<dim3(S2 / 128, 16), 256, 0, stream>>>(xn + (size_t)base * 512, w1T, f1,
                                                      b1, nullptr, 512, 2048);
    // out = x2 + f1 @ w2 + b2 (f32, in-place per-element on d_out)
    k_gemm<4><<<dim3(S2 / 128, 4), 256, 0, stream>>>(f1, w2T,
                                                     (float*)d_out + (size_t)base * 512,
                                                     b2, (const float*)d_out + (size_t)base * 512,
                                                     2048, 512);
  }
}

// Round 3
// 1118.369 us; speedup vs baseline: 1.0806x; 1.0806x over previous
//
#include <hip/hip_runtime.h>
#include <math.h>

#define NTOK 65536   // B*T = 8*8192
#define T_   8192
#define C_   512

typedef short short8 __attribute__((ext_vector_type(8)));
typedef float f32x4  __attribute__((ext_vector_type(4)));

#define GLDS(gp, lp) __builtin_amdgcn_global_load_lds( \
    (__attribute__((address_space(1))) void*)(void*)(gp), \
    (__attribute__((address_space(3))) void*)(lp), 16, 0, 0)

__device__ __forceinline__ unsigned short f2bf(float f){
  unsigned x = __float_as_uint(f);
  x += 0x7fffu + ((x >> 16) & 1u);
  return (unsigned short)(x >> 16);
}
__device__ __forceinline__ float bflo(unsigned p){ return __uint_as_float(p << 16); }
__device__ __forceinline__ float bfhi(unsigned p){ return __uint_as_float(p & 0xffff0000u); }
__device__ __forceinline__ float bfs(unsigned short u){ return __uint_as_float(((unsigned)u) << 16); }
__device__ __forceinline__ unsigned pack2(float a, float b){
  return (unsigned)f2bf(a) | ((unsigned)f2bf(b) << 16);
}

// ---------------- weight prep ----------------
__global__ __launch_bounds__(256) void k_convert(const float* __restrict__ src,
                                                 unsigned short* __restrict__ dst, int n){
  int i = blockIdx.x * 256 + threadIdx.x;
  if (i < n) dst[i] = f2bf(src[i]);
}
// LDS-tiled coalesced transpose: src R x S f32 row-major -> dst S x R bf16.
// R, S multiples of 64. grid = (R/64)*(S/64), 256 threads.
__global__ __launch_bounds__(256) void k_transpose_t(const float* __restrict__ src,
                                                     unsigned short* __restrict__ dst,
                                                     int R, int S){
  __shared__ float tile[64][65];
  int ntS = S >> 6;
  int tr = blockIdx.x / ntS, ts = blockIdx.x - tr * ntS;
  int tx = threadIdx.x & 63, tg = threadIdx.x >> 6;
  #pragma unroll
  for (int rr = tg; rr < 64; rr += 4)
    tile[rr][tx] = src[(size_t)(tr * 64 + rr) * S + ts * 64 + tx];
  __syncthreads();
  #pragma unroll
  for (int rr = tg; rr < 64; rr += 4)
    dst[(size_t)(ts * 64 + rr) * R + tr * 64 + tx] = f2bf(tile[tx][rr]);
}

// ---------------- layernorm: one block per row (C=512) ----------------
__global__ __launch_bounds__(256) void k_ln(const float* __restrict__ x,
                                            const float* __restrict__ g,
                                            const float* __restrict__ b,
                                            unsigned* __restrict__ outbf){
  int row = blockIdx.x;
  int t = threadIdx.x;
  float2 v = ((const float2*)(x + (size_t)row * C_))[t];
  float s = v.x + v.y, ss = v.x * v.x + v.y * v.y;
  #pragma unroll
  for (int o = 32; o; o >>= 1){ s += __shfl_down(s, o); ss += __shfl_down(ss, o); }
  __shared__ float red[8];
  if ((t & 63) == 0){ red[t >> 6] = s; red[4 + (t >> 6)] = ss; }
  __syncthreads();
  float S = red[0] + red[1] + red[2] + red[3];
  float Q = red[4] + red[5] + red[6] + red[7];
  float mu  = S * (1.0f / C_);
  float var = Q * (1.0f / C_) - mu * mu;
  float rs = rsqrtf(var + 1e-5f);
  float y0 = (v.x - mu) * rs * g[2*t]   + b[2*t];
  float y1 = (v.y - mu) * rs * g[2*t+1] + b[2*t+1];
  outbf[(size_t)row * 256 + t] = pack2(y0, y1);
}

// ---------------- depthwise causal conv K=3 over T, chunk-local output ----------------
__global__ __launch_bounds__(256) void k_conv(const unsigned* __restrict__ xn,
                                              const float* __restrict__ w,     // C*3
                                              const float* __restrict__ bias,  // C
                                              unsigned* __restrict__ loc,      // chunk-local
                                              int base){
  size_t idx = (size_t)blockIdx.x * 256 + threadIdx.x;
  size_t n = (idx >> 8) + (size_t)base;   // global token index
  int cp = (int)(idx & 255);              // channel pair
  int t = (int)(n & (T_ - 1));
  unsigned v0 = xn[n * 256 + cp];
  unsigned v1 = (t >= 1) ? xn[(n - 1) * 256 + cp] : 0u;
  unsigned v2 = (t >= 2) ? xn[(n - 2) * 256 + cp] : 0u;
  int c = cp * 2;
  // out[t] = x[t]*w[2] + x[t-1]*w[1] + x[t-2]*w[0]  (cross-correlation, pad (2,0))
  float r0 = bias[c]     + bflo(v0)*w[c*3+2] + bflo(v1)*w[c*3+1] + bflo(v2)*w[c*3+0];
  float r1 = bias[c + 1] + bfhi(v0)*w[c*3+5] + bfhi(v1)*w[c*3+4] + bfhi(v2)*w[c*3+3];
  loc[idx] = pack2(r0, r1);
}

// ---------------- in-place row softmax over M=512, bf16 ----------------
__global__ __launch_bounds__(256) void k_softmax_ip(unsigned* __restrict__ sw){
  int row = blockIdx.x;
  int t = threadIdx.x;
  unsigned p = sw[(size_t)row * 256 + t];
  float vx = bflo(p), vy = bfhi(p);
  float mx = fmaxf(vx, vy);
  #pragma unroll
  for (int o = 32; o; o >>= 1) mx = fmaxf(mx, __shfl_xor(mx, o));
  __shared__ float red[8];
  int w = t >> 6;
  if ((t & 63) == 0) red[w] = mx;
  __syncthreads();
  mx = fmaxf(fmaxf(red[0], red[1]), fmaxf(red[2], red[3]));
  float e0 = __expf(vx - mx), e1 = __expf(vy - mx);
  float s = e0 + e1;
  #pragma unroll
  for (int o = 32; o; o >>= 1) s += __shfl_xor(s, o);
  if ((t & 63) == 0) red[4 + w] = s;
  __syncthreads();
  float inv = 1.0f / (red[4] + red[5] + red[6] + red[7]);
  sw[(size_t)row * 256 + t] = pack2(e0 * inv, e1 * inv);
}

// ---------------- bf16 MFMA GEMM, 128x128 tile, BK=32, 4 waves ----------------
// A: M x K bf16 row-major. Bt: N x K bf16 row-major (B^T layout).
// EPI: 1=bf16, 3=gelu(acc+bias)->bf16, 4=acc+bias+add->f32
template<int EPI>
__global__ __launch_bounds__(256) void k_gemm(const unsigned short* __restrict__ A,
                                              const unsigned short* __restrict__ Bt,
                                              void* __restrict__ out,
                                              const float* __restrict__ bias,
                                              const float* __restrict__ add,
                                              int K, int N){
  __shared__ char smem[16384];   // A tile 8KB | B tile 8KB, each [128][32] bf16
  const int tid  = threadIdx.x;
  const int lane = tid & 63;
  const int w    = tid >> 6;
  const int wr   = w >> 1, wc = w & 1;
  const long brow = (long)blockIdx.x * 128;
  const long bcol = (long)blockIdx.y * 128;

  f32x4 acc[4][4];
  #pragma unroll
  for (int i = 0; i < 4; i++)
    #pragma unroll
    for (int j = 0; j < 4; j++){ f32x4 z = {0.f,0.f,0.f,0.f}; acc[i][j] = z; }

  const char* Abase = (const char*)(A + brow * K);
  const char* Bbase = (const char*)(Bt + bcol * K);
  const int r0 = tid >> 2;            // row within tile for staging
  const int c0 = (tid & 3) * 16;      // byte offset within 64B row
  char* sA = smem;
  char* sB = smem + 8192;
  const unsigned wbase = (unsigned)(w * 1024);   // wave-uniform LDS base

  for (int k0 = 0; k0 < K; k0 += 32){
    __syncthreads();
    {
      const char* g0 = Abase + ((long)r0 * K + k0) * 2 + c0;
      const char* g1 = Abase + ((long)(64 + r0) * K + k0) * 2 + c0;
      GLDS(g0, sA + wbase);
      GLDS(g1, sA + 4096 + wbase);
      const char* h0 = Bbase + ((long)r0 * K + k0) * 2 + c0;
      const char* h1 = Bbase + ((long)(64 + r0) * K + k0) * 2 + c0;
      GLDS(h0, sB + wbase);
      GLDS(h1, sB + 4096 + wbase);
    }
    __syncthreads();
    short8 af[4], bfr[4];
    const int lr = lane & 15;
    const int lk = (lane >> 4) * 16;
    #pragma unroll
    for (int mi = 0; mi < 4; mi++)
      af[mi] = *(const short8*)(sA + (wr * 64 + mi * 16 + lr) * 64 + lk);
    #pragma unroll
    for (int ni = 0; ni < 4; ni++)
      bfr[ni] = *(const short8*)(sB + (wc * 64 + ni * 16 + lr) * 64 + lk);
    #pragma unroll
    for (int mi = 0; mi < 4; mi++)
      #pragma unroll
      for (int ni = 0; ni < 4; ni++)
        acc[mi][ni] = __builtin_amdgcn_mfma_f32_16x16x32_bf16(af[mi], bfr[ni], acc[mi][ni], 0, 0, 0);
  }

  // epilogue: C/D layout col=lane&15, row=(lane>>4)*4+j
  const long rbase = brow + wr * 64;
  const int  cbase = (int)bcol + wc * 64;
  #pragma unroll
  for (int mi = 0; mi < 4; mi++){
    #pragma unroll
    for (int ni = 0; ni < 4; ni++){
      long rg0 = rbase + mi * 16 + (lane >> 4) * 4;
      int  cg  = cbase + ni * 16 + (lane & 15);
      #pragma unroll
      for (int j = 0; j < 4; j++){
        long rg = rg0 + j;
        long oi = rg * (long)N + cg;
        float v = acc[mi][ni][j];
        if (EPI == 1){
          ((unsigned short*)out)[oi] = f2bf(v);
        } else if (EPI == 3){
          v += bias[cg];
          v = 0.5f * v * (1.0f + erff(v * 0.70710678118654752f));
          ((unsigned short*)out)[oi] = f2bf(v);
        } else {
          v += bias[cg] + add[oi];
          ((float*)out)[oi] = v;
        }
      }
    }
  }
}

// ------- fused gates GEMM + sigmoid + gated combine + residual -> x2 (f32) -------
// Block tile: 128 rows x 64 cols of BOTH gate halves (lg at bcol, gg at 512+bcol).
// grid = (S/128, 8). acc regs halved vs r1 (64) -> 2 waves/SIMD occupancy.
__global__ __launch_bounds__(256, 2) void k_gatecomb(const unsigned short* __restrict__ A,
                                                     const unsigned short* __restrict__ Bt,
                                                     const float* __restrict__ gb,      // 1024
                                                     const unsigned short* __restrict__ loc,
                                                     const unsigned short* __restrict__ ctx,
                                                     const float* __restrict__ x,
                                                     float* __restrict__ x2){
  __shared__ char smem[16384];   // A 8KB | Bl 4KB | Bg 4KB
  const int tid  = threadIdx.x;
  const int lane = tid & 63;
  const int w    = tid >> 6;
  const int wr   = w >> 1, wc = w & 1;
  const long brow = (long)blockIdx.x * 128;
  const int  bcol = blockIdx.y * 64;
  const int K = 512;

  f32x4 accL[4][2], accG[4][2];
  #pragma unroll
  for (int i = 0; i < 4; i++)
    #pragma unroll
    for (int j = 0; j < 2; j++){
      f32x4 z = {0.f,0.f,0.f,0.f}; accL[i][j] = z; accG[i][j] = z;
    }

  const char* Abase  = (const char*)(A + brow * (long)K);
  const char* Blbase = (const char*)(Bt + (long)bcol * K);
  const char* Bgbase = (const char*)(Bt + (long)(512 + bcol) * K);
  const int r0 = tid >> 2;
  const int c0 = (tid & 3) * 16;
  char* sA  = smem;
  char* sBl = smem + 8192;
  char* sBg = smem + 12288;
  const unsigned wbase = (unsigned)(w * 1024);

  for (int k0 = 0; k0 < K; k0 += 32){
    __syncthreads();
    GLDS(Abase  + ((long)r0 * K + k0) * 2 + c0,        sA  + wbase);
    GLDS(Abase  + ((long)(64 + r0) * K + k0) * 2 + c0, sA  + 4096 + wbase);
    GLDS(Blbase + ((long)r0 * K + k0) * 2 + c0,        sBl + wbase);
    GLDS(Bgbase + ((long)r0 * K + k0) * 2 + c0,        sBg + wbase);
    __syncthreads();
    short8 af[4], bl[2], bg[2];
    const int lr = lane & 15;
    const int lk = (lane >> 4) * 16;
    #pragma unroll
    for (int mi = 0; mi < 4; mi++)
      af[mi] = *(const short8*)(sA + (wr * 64 + mi * 16 + lr) * 64 + lk);
    #pragma unroll
    for (int ni = 0; ni < 2; ni++){
      bl[ni] = *(const short8*)(sBl + (wc * 32 + ni * 16 + lr) * 64 + lk);
      bg[ni] = *(const short8*)(sBg + (wc * 32 + ni * 16 + lr) * 64 + lk);
    }
    #pragma unroll
    for (int mi = 0; mi < 4; mi++)
      #pragma unroll
      for (int ni = 0; ni < 2; ni++){
        accL[mi][ni] = __builtin_amdgcn_mfma_f32_16x16x32_bf16(af[mi], bl[ni], accL[mi][ni], 0, 0, 0);
        accG[mi][ni] = __builtin_amdgcn_mfma_f32_16x16x32_bf16(af[mi], bg[ni], accG[mi][ni], 0, 0, 0);
      }
  }

  const long rbase = brow + wr * 64;
  const int  cb    = bcol + wc * 32;
  #pragma unroll
  for (int mi = 0; mi < 4; mi++){
    #pragma unroll
    for (int ni = 0; ni < 2; ni++){
      long rg0 = rbase + mi * 16 + (lane >> 4) * 4;
      int  cg  = cb + ni * 16 + (lane & 15);
      float bL = gb[cg], bG = gb[512 + cg];
      #pragma unroll
      for (int j = 0; j < 4; j++){
        long rg = rg0 + j;
        long oi = rg * 512 + cg;
        float vL = 1.0f / (1.0f + __expf(-(accL[mi][ni][j] + bL)));
        float vG = 1.0f / (1.0f + __expf(-(accG[mi][ni][j] + bG)));
        float lv = bfs(loc[oi]);
        float cv = bfs(ctx[oi]);
        x2[oi] = x[oi] + vL * lv + vG * cv;
      }
    }
  }
}

// ---------------- launch ----------------
extern "C" void kernel_launch(void* const* d_in, const int* in_sizes, int n_in,
                              void* d_out, int out_size, void* d_ws, size_t ws_size,
                              hipStream_t stream){
  const float* x      = (const float*)d_in[0];
  const float* conv_w = (const float*)d_in[1];
  const float* conv_b = (const float*)d_in[2];
  const float* mb     = (const float*)d_in[3];
  const float* gate_w = (const float*)d_in[4];
  const float* gate_b = (const float*)d_in[5];
  const float* w1     = (const float*)d_in[6];
  const float* b1     = (const float*)d_in[7];
  const float* w2     = (const float*)d_in[8];
  const float* b2     = (const float*)d_in[9];
  const float* ln1g   = (const float*)d_in[10];
  const float* ln1b   = (const float*)d_in[11];
  const float* ln2g   = (const float*)d_in[12];
  const float* ln2b   = (const float*)d_in[13];

  char* ws = (char*)d_ws;
  const size_t MB = 1024ull * 1024ull;
  // weight prep region: 0..8MB
  unsigned short* mb_bf = (unsigned short*)(ws + 0);
  unsigned short* mbT   = (unsigned short*)(ws + 512 * 1024);
  unsigned short* gwT   = (unsigned short*)(ws + 1 * MB);
  unsigned short* w1T   = (unsigned short*)(ws + 2 * MB);
  unsigned short* w2T   = (unsigned short*)(ws + 4 * MB);
  unsigned short* xn    = (unsigned short*)(ws + 8 * MB);   // 64MB; reused as h
  char* region = ws + 72 * MB;

  // chunk size tier from ws_size (deterministic):
  int S;
  if      (ws_size >= 264 * MB) S = 65536;
  else if (ws_size >= 120 * MB) S = 16384;
  else                          S = 4096;
  const int S2 = S / 2;
  const int NC  = NTOK / S;
  const int NC2 = NTOK / S2;

  unsigned short* loc_c = (unsigned short*)(region);
  unsigned short* ctx_c = (unsigned short*)(region + (size_t)S * 1024);
  unsigned short* sco_c = (unsigned short*)(region + (size_t)S * 2048);
  unsigned short* f1    = (unsigned short*)(region);   // reuses loc/ctx after middle phase

  // weight prep (bf16 + coalesced LDS-tiled transposes to N x K layout)
  k_convert    <<<1024, 256, 0, stream>>>(mb, mb_bf, 512 * 512);
  k_transpose_t<<<  64, 256, 0, stream>>>(mb, mbT, 512, 512);
  k_transpose_t<<< 128, 256, 0, stream>>>(gate_w, gwT, 512, 1024);
  k_transpose_t<<< 256, 256, 0, stream>>>(w1, w1T, 512, 2048);
  k_transpose_t<<< 256, 256, 0, stream>>>(w2, w2T, 2048, 512);

  // LN1 -> xn (bf16, full)
  k_ln<<<NTOK, 256, 0, stream>>>(x, ln1g, ln1b, (unsigned*)xn);

  // middle phase, chunked over tokens
  for (int c = 0; c < NC; c++){
    const int base = c * S;
    const unsigned short* xnc = xn + (size_t)base * 512;
    // depthwise causal conv -> local (bf16, chunk-local)
    k_conv<<<S, 256, 0, stream>>>((const unsigned*)xn, conv_w, conv_b,
                                  (unsigned*)loc_c, base);
    // scores = xn @ mb^T (bf16)
    k_gemm<1><<<dim3(S / 128, 4), 256, 0, stream>>>(xnc, mb_bf, sco_c,
                                                    nullptr, nullptr, 512, 512);
    // softmax rows in-place
    k_softmax_ip<<<S, 256, 0, stream>>>((unsigned*)sco_c);
    // ctx = weights @ mb (bf16)
    k_gemm<1><<<dim3(S / 128, 4), 256, 0, stream>>>(sco_c, mbT, ctx_c,
                                                    nullptr, nullptr, 512, 512);
    // gates + sigmoid + combine + residual -> x2 (f32, into d_out)
    k_gatecomb<<<dim3(S / 128, 8), 256, 0, stream>>>(xnc, gwT, gate_b,
                                                     loc_c, ctx_c,
                                                     x + (size_t)base * 512,
                                                     (float*)d_out + (size_t)base * 512);
  }

  // LN2: h = LN(x2) (bf16, reuse xn buffer)
  k_ln<<<NTOK, 256, 0, stream>>>((const float*)d_out, ln2g, ln2b, (unsigned*)xn);

  // FFN, chunked
  for (int c = 0; c < NC2; c++){
    const int base = c * S2;
    // f1 = gelu(h @ w1 + b1) (bf16)
    k_gemm<3><<<dim3(S2 / 128, 16), 256, 0, stream>>>(xn + (size_t)base * 512, w1T, f1,
                                                      b1, nullptr, 512, 2048);
    // out = x2 + f1 @ w2 + b2 (f32, in-place per-element on d_out)
    k_gemm<4><<<dim3(S2 / 128, 4), 256, 0, stream>>>(f1, w2T,
                                                     (float*)d_out + (size_t)base * 512,
                                                     b2, (const float*)d_out + (size_t)base * 512,
                                                     2048, 512);
  }
}

// Round 4
// 1075.767 us; speedup vs baseline: 1.1234x; 1.0396x over previous
//
#include <hip/hip_runtime.h>
#include <math.h>

#define NTOK 65536   // B*T = 8*8192
#define T_   8192
#define C_   512

typedef short short8 __attribute__((ext_vector_type(8)));
typedef float f32x4  __attribute__((ext_vector_type(4)));

#define GLDS(gp, lp) __builtin_amdgcn_global_load_lds( \
    (__attribute__((address_space(1))) void*)(void*)(gp), \
    (__attribute__((address_space(3))) void*)(lp), 16, 0, 0)

__device__ __forceinline__ unsigned short f2bf(float f){
  unsigned x = __float_as_uint(f);
  x += 0x7fffu + ((x >> 16) & 1u);
  return (unsigned short)(x >> 16);
}
__device__ __forceinline__ float bflo(unsigned p){ return __uint_as_float(p << 16); }
__device__ __forceinline__ float bfhi(unsigned p){ return __uint_as_float(p & 0xffff0000u); }
__device__ __forceinline__ float bfs(unsigned short u){ return __uint_as_float(((unsigned)u) << 16); }
__device__ __forceinline__ unsigned pack2(float a, float b){
  return (unsigned)f2bf(a) | ((unsigned)f2bf(b) << 16);
}

// ---------------- weight prep ----------------
__global__ __launch_bounds__(256) void k_convert(const float* __restrict__ src,
                                                 unsigned short* __restrict__ dst, int n){
  int i = blockIdx.x * 256 + threadIdx.x;
  if (i < n) dst[i] = f2bf(src[i]);
}
// LDS-tiled coalesced transpose: src R x S f32 row-major -> dst S x R bf16.
__global__ __launch_bounds__(256) void k_transpose_t(const float* __restrict__ src,
                                                     unsigned short* __restrict__ dst,
                                                     int R, int S){
  __shared__ float tile[64][65];
  int ntS = S >> 6;
  int tr = blockIdx.x / ntS, ts = blockIdx.x - tr * ntS;
  int tx = threadIdx.x & 63, tg = threadIdx.x >> 6;
  #pragma unroll
  for (int rr = tg; rr < 64; rr += 4)
    tile[rr][tx] = src[(size_t)(tr * 64 + rr) * S + ts * 64 + tx];
  __syncthreads();
  #pragma unroll
  for (int rr = tg; rr < 64; rr += 4)
    dst[(size_t)(ts * 64 + rr) * R + tr * 64 + tx] = f2bf(tile[tx][rr]);
}

// ---------------- layernorm: one block per row (C=512) ----------------
__global__ __launch_bounds__(256) void k_ln(const float* __restrict__ x,
                                            const float* __restrict__ g,
                                            const float* __restrict__ b,
                                            unsigned* __restrict__ outbf){
  int row = blockIdx.x;
  int t = threadIdx.x;
  float2 v = ((const float2*)(x + (size_t)row * C_))[t];
  float s = v.x + v.y, ss = v.x * v.x + v.y * v.y;
  #pragma unroll
  for (int o = 32; o; o >>= 1){ s += __shfl_down(s, o); ss += __shfl_down(ss, o); }
  __shared__ float red[8];
  if ((t & 63) == 0){ red[t >> 6] = s; red[4 + (t >> 6)] = ss; }
  __syncthreads();
  float S = red[0] + red[1] + red[2] + red[3];
  float Q = red[4] + red[5] + red[6] + red[7];
  float mu  = S * (1.0f / C_);
  float var = Q * (1.0f / C_) - mu * mu;
  float rs = rsqrtf(var + 1e-5f);
  float y0 = (v.x - mu) * rs * g[2*t]   + b[2*t];
  float y1 = (v.y - mu) * rs * g[2*t+1] + b[2*t+1];
  outbf[(size_t)row * 256 + t] = pack2(y0, y1);
}

// ---------------- in-place row softmax over M=512, bf16 ----------------
__global__ __launch_bounds__(256) void k_softmax_ip(unsigned* __restrict__ sw){
  int row = blockIdx.x;
  int t = threadIdx.x;
  unsigned p = sw[(size_t)row * 256 + t];
  float vx = bflo(p), vy = bfhi(p);
  float mx = fmaxf(vx, vy);
  #pragma unroll
  for (int o = 32; o; o >>= 1) mx = fmaxf(mx, __shfl_xor(mx, o));
  __shared__ float red[8];
  int w = t >> 6;
  if ((t & 63) == 0) red[w] = mx;
  __syncthreads();
  mx = fmaxf(fmaxf(red[0], red[1]), fmaxf(red[2], red[3]));
  float e0 = __expf(vx - mx), e1 = __expf(vy - mx);
  float s = e0 + e1;
  #pragma unroll
  for (int o = 32; o; o >>= 1) s += __shfl_xor(s, o);
  if ((t & 63) == 0) red[4 + w] = s;
  __syncthreads();
  float inv = 1.0f / (red[4] + red[5] + red[6] + red[7]);
  sw[(size_t)row * 256 + t] = pack2(e0 * inv, e1 * inv);
}

// ---------------- bf16 MFMA GEMM, 128x128 tile, BK=32, 4 waves, 2-PHASE dbuf ----------------
// A: M x K bf16 row-major. Bt: N x K bf16 row-major (B^T layout).
// EPI: 1=bf16, 3=gelu(acc+bias)->bf16, 4=acc+bias+add->f32
template<int EPI>
__global__ __launch_bounds__(256) void k_gemm(const unsigned short* __restrict__ A,
                                              const unsigned short* __restrict__ Bt,
                                              void* __restrict__ out,
                                              const float* __restrict__ bias,
                                              const float* __restrict__ add,
                                              int K, int N){
  __shared__ char smem[32768];   // [2] x { A [128][32]bf16 8KB | B 8KB }
  const int tid  = threadIdx.x;
  const int lane = tid & 63;
  const int w    = tid >> 6;
  const int wr   = w >> 1, wc = w & 1;
  const long brow = (long)blockIdx.x * 128;
  const long bcol = (long)blockIdx.y * 128;

  f32x4 acc[4][4];
  #pragma unroll
  for (int i = 0; i < 4; i++)
    #pragma unroll
    for (int j = 0; j < 4; j++){ f32x4 z = {0.f,0.f,0.f,0.f}; acc[i][j] = z; }

  const char* Abase = (const char*)(A + brow * K);
  const char* Bbase = (const char*)(Bt + bcol * K);
  const int r0 = tid >> 2;            // staging row within 64-row half
  const int c0 = (tid & 3) * 16;      // staging byte offset within 64B row
  const unsigned wbase = (unsigned)(w * 1024);
  const int lr = lane & 15;
  const int lk = (lane >> 4) * 16;

  auto STAGE = [&](int buf, int k0){
    char* dA = smem + buf * 16384 + wbase;
    char* dB = smem + buf * 16384 + 8192 + wbase;
    GLDS(Abase + ((long)r0 * K + k0) * 2 + c0,        dA);
    GLDS(Abase + ((long)(64 + r0) * K + k0) * 2 + c0, dA + 4096);
    GLDS(Bbase + ((long)r0 * K + k0) * 2 + c0,        dB);
    GLDS(Bbase + ((long)(64 + r0) * K + k0) * 2 + c0, dB + 4096);
  };
  auto COMPUTE = [&](int buf){
    const char* sAc = smem + buf * 16384;
    const char* sBc = sAc + 8192;
    short8 af[4], bfr[4];
    #pragma unroll
    for (int mi = 0; mi < 4; mi++)
      af[mi] = *(const short8*)(sAc + (wr * 64 + mi * 16 + lr) * 64 + lk);
    #pragma unroll
    for (int ni = 0; ni < 4; ni++)
      bfr[ni] = *(const short8*)(sBc + (wc * 64 + ni * 16 + lr) * 64 + lk);
    #pragma unroll
    for (int mi = 0; mi < 4; mi++)
      #pragma unroll
      for (int ni = 0; ni < 4; ni++)
        acc[mi][ni] = __builtin_amdgcn_mfma_f32_16x16x32_bf16(af[mi], bfr[ni], acc[mi][ni], 0, 0, 0);
  };

  // prologue
  STAGE(0, 0);
  __syncthreads();              // vmcnt(0) drain + barrier
  int cur = 0;
  for (int k0 = 32; k0 < K; k0 += 32){
    STAGE(cur ^ 1, k0);         // issue next tile early: latency hides under MFMA
    COMPUTE(cur);
    __syncthreads();            // drains staged loads + barrier (one per K-step)
    cur ^= 1;
  }
  COMPUTE(cur);

  // epilogue: C/D layout col=lane&15, row=(lane>>4)*4+j
  const long rbase = brow + wr * 64;
  const int  cbase = (int)bcol + wc * 64;
  #pragma unroll
  for (int mi = 0; mi < 4; mi++){
    #pragma unroll
    for (int ni = 0; ni < 4; ni++){
      long rg0 = rbase + mi * 16 + (lane >> 4) * 4;
      int  cg  = cbase + ni * 16 + (lane & 15);
      #pragma unroll
      for (int j = 0; j < 4; j++){
        long rg = rg0 + j;
        long oi = rg * (long)N + cg;
        float v = acc[mi][ni][j];
        if (EPI == 1){
          ((unsigned short*)out)[oi] = f2bf(v);
        } else if (EPI == 3){
          v += bias[cg];
          v = 0.5f * v * (1.0f + erff(v * 0.70710678118654752f));
          ((unsigned short*)out)[oi] = f2bf(v);
        } else {
          v += bias[cg] + add[oi];
          ((float*)out)[oi] = v;
        }
      }
    }
  }
}

// ------- fused gates GEMM + sigmoid + conv + gated combine + residual -> x2 (f32) -------
// 2-phase dbuf. Block tile: 128 rows x 64 cols of BOTH gate halves.
// Conv (depthwise K=3 causal) computed inline in epilogue from xn gathers (L2-hot).
__global__ __launch_bounds__(256, 2) void k_gatecomb(const unsigned short* __restrict__ xn, // full
                                                     const unsigned short* __restrict__ Bt, // gwT
                                                     const float* __restrict__ gb,          // 1024
                                                     const float* __restrict__ cw,          // conv_w C*3
                                                     const float* __restrict__ cbv,         // conv_b C
                                                     const unsigned short* __restrict__ ctx,// chunk-local
                                                     const float* __restrict__ x,           // chunk-offset
                                                     float* __restrict__ x2,                // chunk-offset
                                                     int base){
  __shared__ char smem[32768];   // [2] x { A 8KB | Bl 4KB | Bg 4KB }
  const int tid  = threadIdx.x;
  const int lane = tid & 63;
  const int w    = tid >> 6;
  const int wr   = w >> 1, wc = w & 1;
  const long brow = (long)blockIdx.x * 128;
  const int  bcol = blockIdx.y * 64;
  const int K = 512;

  f32x4 accL[4][2], accG[4][2];
  #pragma unroll
  for (int i = 0; i < 4; i++)
    #pragma unroll
    for (int j = 0; j < 2; j++){
      f32x4 z = {0.f,0.f,0.f,0.f}; accL[i][j] = z; accG[i][j] = z;
    }

  const unsigned short* A = xn + (size_t)base * 512;
  const char* Abase  = (const char*)(A + brow * (long)K);
  const char* Blbase = (const char*)(Bt + (long)bcol * K);
  const char* Bgbase = (const char*)(Bt + (long)(512 + bcol) * K);
  const int r0 = tid >> 2;
  const int c0 = (tid & 3) * 16;
  const unsigned wbase = (unsigned)(w * 1024);
  const int lr = lane & 15;
  const int lk = (lane >> 4) * 16;

  auto STAGE = [&](int buf, int k0){
    char* dA = smem + buf * 16384 + wbase;
    GLDS(Abase  + ((long)r0 * K + k0) * 2 + c0,        dA);
    GLDS(Abase  + ((long)(64 + r0) * K + k0) * 2 + c0, dA + 4096);
    GLDS(Blbase + ((long)r0 * K + k0) * 2 + c0,        dA + 8192);
    GLDS(Bgbase + ((long)r0 * K + k0) * 2 + c0,        dA + 12288);
  };
  auto COMPUTE = [&](int buf){
    const char* sAc  = smem + buf * 16384;
    const char* sBlc = sAc + 8192;
    const char* sBgc = sAc + 12288;
    short8 af[4], bl[2], bg[2];
    #pragma unroll
    for (int mi = 0; mi < 4; mi++)
      af[mi] = *(const short8*)(sAc + (wr * 64 + mi * 16 + lr) * 64 + lk);
    #pragma unroll
    for (int ni = 0; ni < 2; ni++){
      bl[ni] = *(const short8*)(sBlc + (wc * 32 + ni * 16 + lr) * 64 + lk);
      bg[ni] = *(const short8*)(sBgc + (wc * 32 + ni * 16 + lr) * 64 + lk);
    }
    #pragma unroll
    for (int mi = 0; mi < 4; mi++)
      #pragma unroll
      for (int ni = 0; ni < 2; ni++){
        accL[mi][ni] = __builtin_amdgcn_mfma_f32_16x16x32_bf16(af[mi], bl[ni], accL[mi][ni], 0, 0, 0);
        accG[mi][ni] = __builtin_amdgcn_mfma_f32_16x16x32_bf16(af[mi], bg[ni], accG[mi][ni], 0, 0, 0);
      }
  };

  STAGE(0, 0);
  __syncthreads();
  int cur = 0;
  for (int k0 = 32; k0 < K; k0 += 32){
    STAGE(cur ^ 1, k0);
    COMPUTE(cur);
    __syncthreads();
    cur ^= 1;
  }
  COMPUTE(cur);

  const long rbase = brow + wr * 64;
  const int  cb_   = bcol + wc * 32;
  #pragma unroll
  for (int mi = 0; mi < 4; mi++){
    #pragma unroll
    for (int ni = 0; ni < 2; ni++){
      long rg0 = rbase + mi * 16 + (lane >> 4) * 4;
      int  cg  = cb_ + ni * 16 + (lane & 15);
      float bL = gb[cg], bG = gb[512 + cg];
      float w0 = cw[cg * 3], w1 = cw[cg * 3 + 1], w2v = cw[cg * 3 + 2];
      float cbias = cbv[cg];
      #pragma unroll
      for (int j = 0; j < 4; j++){
        long rg = rg0 + j;
        size_t n = (size_t)base + (size_t)rg;    // global token
        int t = (int)(n & (T_ - 1));
        // depthwise causal conv from bf16 xn (L1/L2-hot: same rows just streamed)
        float xv0 = bfs(xn[n * 512 + cg]);
        float xv1 = (t >= 1) ? bfs(xn[(n - 1) * 512 + cg]) : 0.f;
        float xv2 = (t >= 2) ? bfs(xn[(n - 2) * 512 + cg]) : 0.f;
        float lv = cbias + xv0 * w2v + xv1 * w1 + xv2 * w0;
        float vL = 1.0f / (1.0f + __expf(-(accL[mi][ni][j] + bL)));
        float vG = 1.0f / (1.0f + __expf(-(accG[mi][ni][j] + bG)));
        long oi = rg * 512 + cg;
        x2[oi] = x[oi] + vL * lv + vG * bfs(ctx[oi]);
      }
    }
  }
}

// ---------------- launch ----------------
extern "C" void kernel_launch(void* const* d_in, const int* in_sizes, int n_in,
                              void* d_out, int out_size, void* d_ws, size_t ws_size,
                              hipStream_t stream){
  const float* x      = (const float*)d_in[0];
  const float* conv_w = (const float*)d_in[1];
  const float* conv_b = (const float*)d_in[2];
  const float* mb     = (const float*)d_in[3];
  const float* gate_w = (const float*)d_in[4];
  const float* gate_b = (const float*)d_in[5];
  const float* w1     = (const float*)d_in[6];
  const float* b1     = (const float*)d_in[7];
  const float* w2     = (const float*)d_in[8];
  const float* b2     = (const float*)d_in[9];
  const float* ln1g   = (const float*)d_in[10];
  const float* ln1b   = (const float*)d_in[11];
  const float* ln2g   = (const float*)d_in[12];
  const float* ln2b   = (const float*)d_in[13];

  char* ws = (char*)d_ws;
  const size_t MB = 1024ull * 1024ull;
  // weight prep region: 0..8MB
  unsigned short* mb_bf = (unsigned short*)(ws + 0);
  unsigned short* mbT   = (unsigned short*)(ws + 512 * 1024);
  unsigned short* gwT   = (unsigned short*)(ws + 1 * MB);
  unsigned short* w1T   = (unsigned short*)(ws + 2 * MB);
  unsigned short* w2T   = (unsigned short*)(ws + 4 * MB);
  unsigned short* xn    = (unsigned short*)(ws + 8 * MB);   // 64MB; reused as h
  char* region = ws + 72 * MB;

  // chunk size tier from ws_size (deterministic): peak = 72MB + 2*S KB
  int S;
  if      (ws_size >= 200 * MB) S = 65536;
  else if (ws_size >= 104 * MB) S = 16384;
  else                          S = 4096;
  const int S2 = S / 2;
  const int NC  = NTOK / S;
  const int NC2 = NTOK / S2;

  unsigned short* ctx_c = (unsigned short*)(region);
  unsigned short* sco_c = (unsigned short*)(region + (size_t)S * 1024);
  unsigned short* f1    = (unsigned short*)(region);   // reuses ctx/sco after middle phase

  // weight prep (bf16 + coalesced LDS-tiled transposes to N x K layout)
  k_convert    <<<1024, 256, 0, stream>>>(mb, mb_bf, 512 * 512);
  k_transpose_t<<<  64, 256, 0, stream>>>(mb, mbT, 512, 512);
  k_transpose_t<<< 128, 256, 0, stream>>>(gate_w, gwT, 512, 1024);
  k_transpose_t<<< 256, 256, 0, stream>>>(w1, w1T, 512, 2048);
  k_transpose_t<<< 256, 256, 0, stream>>>(w2, w2T, 2048, 512);

  // LN1 -> xn (bf16, full)
  k_ln<<<NTOK, 256, 0, stream>>>(x, ln1g, ln1b, (unsigned*)xn);

  // middle phase, chunked over tokens
  for (int c = 0; c < NC; c++){
    const int base = c * S;
    const unsigned short* xnc = xn + (size_t)base * 512;
    // scores = xn @ mb^T (bf16)
    k_gemm<1><<<dim3(S / 128, 4), 256, 0, stream>>>(xnc, mb_bf, sco_c,
                                                    nullptr, nullptr, 512, 512);
    // softmax rows in-place
    k_softmax_ip<<<S, 256, 0, stream>>>((unsigned*)sco_c);
    // ctx = weights @ mb (bf16)
    k_gemm<1><<<dim3(S / 128, 4), 256, 0, stream>>>(sco_c, mbT, ctx_c,
                                                    nullptr, nullptr, 512, 512);
    // gates GEMM + sigmoid + conv + combine + residual -> x2 (f32, into d_out)
    k_gatecomb<<<dim3(S / 128, 8), 256, 0, stream>>>(xn, gwT, gate_b,
                                                     conv_w, conv_b, ctx_c,
                                                     x + (size_t)base * 512,
                                                     (float*)d_out + (size_t)base * 512,
                                                     base);
  }

  // LN2: h = LN(x2) (bf16, reuse xn buffer)
  k_ln<<<NTOK, 256, 0, stream>>>((const float*)d_out, ln2g, ln2b, (unsigned*)xn);

  // FFN, chunked
  for (int c = 0; c < NC2; c++){
    const int base = c * S2;
    // f1 = gelu(h @ w1 + b1) (bf16)
    k_gemm<3><<<dim3(S2 / 128, 16), 256, 0, stream>>>(xn + (size_t)base * 512, w1T, f1,
                                                      b1, nullptr, 512, 2048);
    // out = x2 + f1 @ w2 + b2 (f32, in-place per-element on d_out)
    k_gemm<4><<<dim3(S2 / 128, 4), 256, 0, stream>>>(f1, w2T,
                                                     (float*)d_out + (size_t)base * 512,
                                                     b2, (const float*)d_out + (size_t)base * 512,
                                                     2048, 512);
  }
}